// Round 2
// baseline (854.745 us; speedup 1.0000x reference)
//
#include <hip/hip_runtime.h>

typedef float f32x4 __attribute__((ext_vector_type(4)));
typedef short short8 __attribute__((ext_vector_type(8)));
typedef unsigned int u32;
typedef unsigned short u16;
typedef u32 u32x2 __attribute__((ext_vector_type(2)));

#define NPG 69   // nodes per graph
#define LM 68    // landmark count / master index
#define TLS 72   // tl2 row stride (words): 72%32=8 -> 32 distinct bank starts
#define CLL 0.25f                     // landmark<-landmark/self coeff
#define CML 0.06019292654288460f      // 0.5/sqrt(69)
#define SELFM 0.014492753623188406f   // 1/69

__device__ __forceinline__ u16 f2bf(float x) {
  u32 b = __float_as_uint(x);
  return (u16)((b + 0x7FFFu + ((b >> 16) & 1u)) >> 16);
}

// prep: (a) swizzle 7 HIDxHID weight mats into bf16 MFMA B-fragments;
//       (b) fold BN into per-layer affine sc/sh.
__global__ void prep(const float* __restrict__ midW, const float* __restrict__ lastW,
                     const float* __restrict__ bng, const float* __restrict__ bnb,
                     const float* __restrict__ bnm, const float* __restrict__ bnv,
                     u16* __restrict__ frag, float* __restrict__ bns) {
  const int t0 = blockIdx.x * blockDim.x + threadIdx.x;
  for (int u = t0; u < 7 * 4 * 2 * 64; u += gridDim.x * blockDim.x) {
    const int lane = u & 63;
    const int t = u >> 6;
    const int ks = t & 1;
    const int nt = (t >> 1) & 3;
    const int l = t >> 3;  // 0..6 -> layers 1..7
    const float* W = (l < 6) ? (midW + l * 4096) : lastW;
    const int col = nt * 16 + (lane & 15);
    const int kb = ks * 32 + (lane >> 4) * 8;
    u16* dst = frag + (size_t)u * 8;
#pragma unroll
    for (int j = 0; j < 8; ++j) dst[j] = f2bf(W[(kb + j) * 64 + col]);
  }
  for (int u = t0; u < 7 * 64; u += gridDim.x * blockDim.x) {
    const int l = u >> 6, f = u & 63;
    const float sc = (float)((double)bng[l * 64 + f] / sqrt((double)bnv[l * 64 + f] + 1e-5));
    bns[l * 128 + f] = sc;
    bns[l * 128 + 64 + f] = bnb[l * 64 + f] - bnm[l * 64 + f] * sc;
  }
}

__launch_bounds__(256, 5)
__global__ void gcn_fused(
    const float* __restrict__ x,
    const float* __restrict__ cfW, const float* __restrict__ cfb,
    const float* __restrict__ cmb, const float* __restrict__ clb,
    const float* __restrict__ aW1, const float* __restrict__ ab1,
    const float* __restrict__ aW2, const float* __restrict__ ab2,
    const float* __restrict__ f1W, const float* __restrict__ f1b,
    const float* __restrict__ f2W, const float* __restrict__ f2b,
    const u16* __restrict__ frag, const float* __restrict__ bns,
    float* __restrict__ out) {
  // LDS budget: 8960 + 20736 + 1024 + 256 + 768 = 31744 B -> 5 blocks/CU
  __shared__ u16 hb[70 * 64];        // bf16 h (+master row 68, q row 69), XOR-swizzled
  __shared__ float tl2[72 * TLS];    // fp32 t, ghost rows: [0]=t67 [1..68]=t0..67 [69]=t0 [70]=t68 [71]=t_q
  __shared__ float wsum[4 * 64];     // per-wave landmark h partial sums
  __shared__ float mrow[64];         // final master h (for attention)
  __shared__ float gv[192];          // readout concat [mean|max|master*att]

  const int tid = threadIdx.x;
  const int g = blockIdx.x;
  const int lane = tid & 63;
  const int wv = tid >> 6;
  const int p15 = lane & 15;
  const int qg = lane >> 4;
  const int ec = tid >> 4;          // node-chunk id 0..15
  const int f0 = (tid & 15) * 4;    // feature quad

  f32x4 h_reg[5];                   // this thread's h (residual/readout state)
  f32x4 h_m;                        // master h (valid on tid<16)

  // bf16 store into swizzled hb
  auto store_hb = [&](int nrow, int fq, f32x4 v) {
    const int base = (nrow * 64 + fq) ^ ((nrow & 7) << 3);
    u32x2 w;
    w.x = (u32)f2bf(v[0]) | ((u32)f2bf(v[1]) << 16);
    w.y = (u32)f2bf(v[2]) | ((u32)f2bf(v[3]) << 16);
    *(u32x2*)&hb[base] = w;
  };

  // ---- shared epilogue: stencil agg + bias + relu + bn + resid; maintains q row
  auto epilogue = [&](const float* bias_p, const float* bns_l, bool resid, bool last) {
    const f32x4 bias = *(const f32x4*)&bias_p[f0];
    f32x4 sc = {1.f, 1.f, 1.f, 1.f}, sh = {0.f, 0.f, 0.f, 0.f};
    if (bns_l) {
      sc = *(const f32x4*)&bns_l[f0];
      sh = *(const f32x4*)&bns_l[64 + f0];
    }
    const f32x4 tm = *(const f32x4*)&tl2[70 * TLS + f0];  // t[master]
    f32x4 hsum = {0.f, 0.f, 0.f, 0.f};
#pragma unroll
    for (int it = 0; it < 5; ++it) {
      const int n = it * 16 + ec;
      if (n < LM) {
        const f32x4 ta = *(const f32x4*)&tl2[n * TLS + f0];        // t[n-1]
        const f32x4 ts = *(const f32x4*)&tl2[(n + 1) * TLS + f0];  // t[n]
        const f32x4 tb = *(const f32x4*)&tl2[(n + 2) * TLS + f0];  // t[n+1]
        f32x4 o;
#pragma unroll
        for (int e = 0; e < 4; ++e) {
          float v = CLL * (ta[e] + ts[e] + tb[e]) + CML * tm[e] + bias[e];
          v = fmaxf(v, 0.f);
          v = v * sc[e] + sh[e];
          if (resid) v += h_reg[it][e];
          o[e] = v;
          hsum[e] += v;
        }
        h_reg[it] = o;
        store_hb(n, f0, o);
      }
    }
#pragma unroll
    for (int e = 0; e < 4; ++e) {
      hsum[e] += __shfl_xor(hsum[e], 16, 64);
      hsum[e] += __shfl_xor(hsum[e], 32, 64);
    }
    if (lane < 16) *(f32x4*)&wsum[wv * 64 + lane * 4] = hsum;
    __syncthreads();  // B2
    if (tid < 16) {   // master node + q row for next layer
      f32x4 S;
#pragma unroll
      for (int e = 0; e < 4; ++e)
        S[e] = wsum[f0 + e] + wsum[64 + f0 + e] + wsum[128 + f0 + e] + wsum[192 + f0 + e];
      const f32x4 zm = *(const f32x4*)&tl2[71 * TLS + f0];  // aggregated master t (q-row)
      f32x4 om, q;
#pragma unroll
      for (int e = 0; e < 4; ++e) {
        float v = zm[e] + bias[e];
        v = fmaxf(v, 0.f);
        v = v * sc[e] + sh[e];
        if (resid) v += h_m[e];
        om[e] = v;
        q[e] = CML * S[e] + SELFM * v;
      }
      h_m = om;
      store_hb(LM, f0, om);
      store_hb(69, f0, q);
      if (last) *(f32x4*)&mrow[f0] = om;
    }
    __syncthreads();  // B3
  };

  // prefetch layer-1 W fragments
  const u16* fb1 = frag + (((size_t)(0 * 4 + wv) * 2) * 64 + lane) * 8;
  short8 b0 = *(const short8*)fb1;
  short8 b1 = *(const short8*)(fb1 + 512);

  // ---- layer 0: t = [x ; q_x] @ W_first in exact fp32 (K=4)
  {
    float w0[4];
#pragma unroll
    for (int k = 0; k < 4; ++k) w0[k] = cfW[k * 64 + lane];
    const float* xg = x + (size_t)g * NPG * 4;
    f32x4 qx;
    {
      const f32x4 xa = *(const f32x4*)&xg[lane * 4];
#pragma unroll
      for (int e = 0; e < 4; ++e) qx[e] = CML * xa[e];
      if (lane < 5) {
        const f32x4 xb = *(const f32x4*)&xg[(64 + lane) * 4];
        const float c = (lane == 4) ? SELFM : CML;
#pragma unroll
        for (int e = 0; e < 4; ++e) qx[e] += c * xb[e];
      }
#pragma unroll
      for (int off = 32; off > 0; off >>= 1)
#pragma unroll
        for (int e = 0; e < 4; ++e) qx[e] += __shfl_xor(qx[e], off, 64);
    }
#pragma unroll
    for (int it = 0; it < 18; ++it) {
      const int n = wv + it * 4;
      if (n < 70) {
        f32x4 xv;
        if (n == 69) xv = qx;
        else xv = *(const f32x4*)&xg[n * 4];
        const float t = xv[0] * w0[0] + xv[1] * w0[1] + xv[2] * w0[2] + xv[3] * w0[3];
        const int idx = n + 1 + (n >= 68);
        tl2[idx * TLS + lane] = t;
        if (n == 0) tl2[69 * TLS + lane] = t;
        if (n == 67) tl2[lane] = t;
      }
    }
  }
  __syncthreads();  // B1 (layer 0)
  epilogue(cfb, bns, false, false);

  // ---- layers 1..7: t = h @ W via bf16 MFMA
#pragma unroll 1
  for (int l = 1; l <= 7; ++l) {
    short8 nb0, nb1;
    if (l < 7) {  // prefetch next layer's fragments
      const u16* fb = frag + (((size_t)(l * 4 + wv) * 2) * 64 + lane) * 8;
      nb0 = *(const short8*)fb;
      nb1 = *(const short8*)(fb + 512);
    }
    const int col = wv * 16 + p15;
#pragma unroll
    for (int mt = 0; mt < 5; ++mt) {
      int row = mt * 16 + p15;
      if (row > 69) row = 69;  // clamp: keep reads in hb, rows >=70 discarded anyway
      const int sw = (row & 7) << 3;
      const short8 a0 = *(const short8*)&hb[(row * 64 + qg * 8) ^ sw];
      const short8 a1 = *(const short8*)&hb[(row * 64 + 32 + qg * 8) ^ sw];
      f32x4 acc = {0.f, 0.f, 0.f, 0.f};
      acc = __builtin_amdgcn_mfma_f32_16x16x32_bf16(a0, b0, acc, 0, 0, 0);
      acc = __builtin_amdgcn_mfma_f32_16x16x32_bf16(a1, b1, acc, 0, 0, 0);
      const int rb = mt * 16 + qg * 4;
#pragma unroll
      for (int r = 0; r < 4; ++r) {
        const int rh = rb + r;
        if (rh < 70) {
          const int idx = rh + 1 + (rh >= 68);
          tl2[idx * TLS + col] = acc[r];
          if (rh == 0) tl2[69 * TLS + col] = acc[r];
          if (rh == 67) tl2[col] = acc[r];
        }
      }
    }
    b0 = nb0;
    b1 = nb1;
    __syncthreads();  // B1
    if (l < 7) epilogue(cmb + (l - 1) * 64, bns + l * 128, true, false);
    else epilogue(clb, nullptr, false, true);
  }

  // ---- readout
  {
    float* rsum = tl2;        // scratch (tl2 is dead now)
    float* rmax = tl2 + 256;
    f32x4 s = {0.f, 0.f, 0.f, 0.f};
    f32x4 m = {-3.402823466e38f, -3.402823466e38f, -3.402823466e38f, -3.402823466e38f};
#pragma unroll
    for (int it = 0; it < 5; ++it) {
      const int n = it * 16 + ec;
      if (n < LM) {
#pragma unroll
        for (int e = 0; e < 4; ++e) {
          s[e] += h_reg[it][e];
          m[e] = fmaxf(m[e], h_reg[it][e]);
        }
      }
    }
#pragma unroll
    for (int e = 0; e < 4; ++e) {
      s[e] += __shfl_xor(s[e], 16, 64);
      s[e] += __shfl_xor(s[e], 32, 64);
      m[e] = fmaxf(m[e], __shfl_xor(m[e], 16, 64));
      m[e] = fmaxf(m[e], __shfl_xor(m[e], 32, 64));
    }
    if (lane < 16) {
      *(f32x4*)&rsum[wv * 64 + lane * 4] = s;
      *(f32x4*)&rmax[wv * 64 + lane * 4] = m;
    }
    if (tid < 64) {  // attention gate on master (mrow written at layer-7 finalize)
      float z = ab1[tid];
      for (int k = 0; k < 64; ++k) z += mrow[k] * aW1[k * 64 + tid];
      z = fmaxf(z, 0.f);
      float pr = z * aW2[tid];
#pragma unroll
      for (int off = 32; off > 0; off >>= 1) pr += __shfl_xor(pr, off, 64);
      const float att = 1.f / (1.f + expf(-(pr + ab2[0])));
      gv[128 + tid] = mrow[tid] * att;
    }
    __syncthreads();
    if (tid < 16) {
      f32x4 S, M;
#pragma unroll
      for (int e = 0; e < 4; ++e) {
        S[e] = rsum[f0 + e] + rsum[64 + f0 + e] + rsum[128 + f0 + e] + rsum[192 + f0 + e];
        M[e] = fmaxf(fmaxf(rmax[f0 + e], rmax[64 + f0 + e]),
                     fmaxf(rmax[128 + f0 + e], rmax[192 + f0 + e]));
        gv[f0 + e] = S[e] * (1.f / 68.f);
        gv[64 + f0 + e] = M[e];
      }
    }
    __syncthreads();
    if (tid < 64) {  // fc1 + relu + fc2
      float a1 = f1b[tid];
      for (int i = 0; i < 192; ++i) a1 += gv[i] * f1W[i * 64 + tid];
      const float y = fmaxf(a1, 0.f);
      float po[7];
#pragma unroll
      for (int o = 0; o < 7; ++o) po[o] = y * f2W[tid * 7 + o];
#pragma unroll
      for (int o = 0; o < 7; ++o)
#pragma unroll
        for (int off = 32; off > 0; off >>= 1) po[o] += __shfl_xor(po[o], off, 64);
      if (tid == 0) {
#pragma unroll
        for (int o = 0; o < 7; ++o) out[(size_t)g * 7 + o] = po[o] + f2b[o];
      }
    }
  }
}

extern "C" void kernel_launch(void* const* d_in, const int* in_sizes, int n_in,
                              void* d_out, int out_size, void* d_ws, size_t ws_size,
                              hipStream_t stream) {
  (void)in_sizes; (void)n_in; (void)ws_size;
  const float* x   = (const float*)d_in[0];
  const float* cfW = (const float*)d_in[4];
  const float* cfb = (const float*)d_in[5];
  const float* cmW = (const float*)d_in[6];
  const float* cmb = (const float*)d_in[7];
  const float* clW = (const float*)d_in[8];
  const float* clb = (const float*)d_in[9];
  const float* bng = (const float*)d_in[10];
  const float* bnb = (const float*)d_in[11];
  const float* bnm = (const float*)d_in[12];
  const float* bnv = (const float*)d_in[13];
  const float* aW1 = (const float*)d_in[14];
  const float* ab1 = (const float*)d_in[15];
  const float* aW2 = (const float*)d_in[16];
  const float* ab2 = (const float*)d_in[17];
  const float* f1W = (const float*)d_in[18];
  const float* f1b = (const float*)d_in[19];
  const float* f2W = (const float*)d_in[20];
  const float* f2b = (const float*)d_in[21];

  u16* frag = (u16*)d_ws;                              // 57344 B
  float* bns = (float*)((char*)d_ws + 57344);          // 7*128 floats
  const int ngraphs = out_size / 7;

  prep<<<dim3(16), dim3(256), 0, stream>>>(cmW, clW, bng, bnb, bnm, bnv, frag, bns);
  gcn_fused<<<dim3(ngraphs), dim3(256), 0, stream>>>(
      x, cfW, cfb, cmb, clb, aW1, ab1, aW2, ab2, f1W, f1b, f2W, f2b,
      frag, bns, (float*)d_out);
}

// Round 3
// 328.954 us; speedup vs baseline: 2.5984x; 2.5984x over previous
//
#include <hip/hip_runtime.h>

typedef float f32x4 __attribute__((ext_vector_type(4)));
typedef short short8 __attribute__((ext_vector_type(8)));
typedef unsigned int u32;
typedef unsigned short u16;
typedef u32 u32x2 __attribute__((ext_vector_type(2)));

#define NPG 69   // nodes per graph
#define LM 68    // landmark count / master index
#define TLS 68   // tl2 row stride (words); 4*68 % 32 = 16 -> 2-way on MFMA col-writes
#define CLL 0.25f                     // landmark<-landmark/self coeff
#define CML 0.06019292654288460f      // 0.5/sqrt(69)
#define SELFM 0.014492753623188406f   // 1/69

__device__ __forceinline__ u16 f2bf(float x) {
  u32 b = __float_as_uint(x);
  return (u16)((b + 0x7FFFu + ((b >> 16) & 1u)) >> 16);
}

__device__ __forceinline__ void store_hb(u16* hb, int nrow, int fq, f32x4 v) {
  const int base = (nrow * 64 + fq) ^ ((nrow & 7) << 3);  // 16B-block XOR swizzle
  u32x2 w;
  w.x = (u32)f2bf(v[0]) | ((u32)f2bf(v[1]) << 16);
  w.y = (u32)f2bf(v[2]) | ((u32)f2bf(v[3]) << 16);
  *(u32x2*)&hb[base] = w;
}

// prep: (a) swizzle 7 HIDxHID weight mats into bf16 MFMA B-fragments;
//       (b) fold BN into per-layer affine sc/sh.
__global__ void prep(const float* __restrict__ midW, const float* __restrict__ lastW,
                     const float* __restrict__ bng, const float* __restrict__ bnb,
                     const float* __restrict__ bnm, const float* __restrict__ bnv,
                     u16* __restrict__ frag, float* __restrict__ bns) {
  const int t0 = blockIdx.x * blockDim.x + threadIdx.x;
  for (int u = t0; u < 7 * 4 * 2 * 64; u += gridDim.x * blockDim.x) {
    const int lane = u & 63;
    const int t = u >> 6;
    const int ks = t & 1;
    const int nt = (t >> 1) & 3;
    const int l = t >> 3;  // 0..6 -> layers 1..7
    const float* W = (l < 6) ? (midW + l * 4096) : lastW;
    const int col = nt * 16 + (lane & 15);
    const int kb = ks * 32 + (lane >> 4) * 8;
    u16* dst = frag + (size_t)u * 8;
#pragma unroll
    for (int j = 0; j < 8; ++j) dst[j] = f2bf(W[(kb + j) * 64 + col]);
  }
  for (int u = t0; u < 7 * 64; u += gridDim.x * blockDim.x) {
    const int l = u >> 6, f = u & 63;
    const float sc = (float)((double)bng[l * 64 + f] / sqrt((double)bnv[l * 64 + f] + 1e-5));
    bns[l * 128 + f] = sc;
    bns[l * 128 + 64 + f] = bnb[l * 64 + f] - bnm[l * 64 + f] * sc;
  }
}

// ---- epilogue macros: ALL state in named registers, ALL indices compile-time.
#define EPI_CHUNK(IT, H, RESID, LAST)                                        \
  do {                                                                       \
    const int n_ = (IT) * 16 + ec;                                           \
    const f32x4 ta_ = *(const f32x4*)&tl2[n_ * TLS + f0];                    \
    const f32x4 ts_ = *(const f32x4*)&tl2[(n_ + 1) * TLS + f0];              \
    const f32x4 tb_ = *(const f32x4*)&tl2[(n_ + 2) * TLS + f0];              \
    f32x4 o_;                                                                \
    _Pragma("unroll") for (int e = 0; e < 4; ++e) {                          \
      float v_ = CLL * (ta_[e] + ts_[e] + tb_[e]) + CML * tm_[e] + bias_[e]; \
      v_ = fmaxf(v_, 0.f);                                                   \
      v_ = v_ * sc_[e] + sh_[e];                                             \
      if (RESID) v_ += H[e];                                                 \
      o_[e] = v_;                                                            \
    }                                                                        \
    H = o_;                                                                  \
    if (!(LAST)) store_hb(hb, n_, f0, o_);                                   \
  } while (0)

#define EPILOGUE(BIASP, BNSP, RESID, LAST, L0)                               \
  do {                                                                       \
    const f32x4 bias_ = *(const f32x4*)&(BIASP)[f0];                         \
    f32x4 sc_, sh_;                                                          \
    const float* bnsp_ = (BNSP);                                             \
    if (bnsp_) {                                                             \
      sc_ = *(const f32x4*)&bnsp_[f0];                                       \
      sh_ = *(const f32x4*)&bnsp_[64 + f0];                                  \
    } else {                                                                 \
      sc_ = (f32x4){1.f, 1.f, 1.f, 1.f};                                     \
      sh_ = (f32x4){0.f, 0.f, 0.f, 0.f};                                     \
    }                                                                        \
    const f32x4 tm_ = *(const f32x4*)&tl2[70 * TLS + f0];                    \
    EPI_CHUNK(0, h0, RESID, LAST);                                           \
    EPI_CHUNK(1, h1, RESID, LAST);                                           \
    EPI_CHUNK(2, h2, RESID, LAST);                                           \
    EPI_CHUNK(3, h3, RESID, LAST);                                           \
    if (ec < 4) EPI_CHUNK(4, h4, RESID, LAST);                               \
    if (tid < 16) {                                                          \
      f32x4 zm_;                                                             \
      if (L0) {                                                              \
        _Pragma("unroll") for (int e = 0; e < 4; ++e) zm_[e] =               \
            qsum[f0 + e] + qsum[64 + f0 + e] + qsum[128 + f0 + e] +          \
            qsum[192 + f0 + e];                                              \
      } else {                                                               \
        zm_ = *(const f32x4*)&tl2[71 * TLS + f0];                            \
      }                                                                      \
      f32x4 om_;                                                             \
      _Pragma("unroll") for (int e = 0; e < 4; ++e) {                        \
        float v_ = zm_[e] + bias_[e];                                        \
        v_ = fmaxf(v_, 0.f);                                                 \
        v_ = v_ * sc_[e] + sh_[e];                                           \
        if (RESID) v_ += hm[e];                                              \
        om_[e] = v_;                                                         \
      }                                                                      \
      hm = om_;                                                              \
      if (!(LAST)) store_hb(hb, LM, f0, om_);                                \
      else *(f32x4*)&mrow[f0] = om_;                                         \
    }                                                                        \
    __syncthreads();                                                         \
  } while (0)

__launch_bounds__(256, 5)
__global__ void gcn_fused(
    const float* __restrict__ x,
    const float* __restrict__ cfW, const float* __restrict__ cfb,
    const float* __restrict__ cmb, const float* __restrict__ clb,
    const float* __restrict__ aW1, const float* __restrict__ ab1,
    const float* __restrict__ aW2, const float* __restrict__ ab2,
    const float* __restrict__ f1W, const float* __restrict__ f1b,
    const float* __restrict__ f2W, const float* __restrict__ f2b,
    const u16* __restrict__ frag, const float* __restrict__ bns,
    float* __restrict__ out) {
  // LDS: 8960 + 19584 + 1024 + 256 + 768 = 30592 B -> 5 blocks/CU (20 waves)
  __shared__ u16 hb[70 * 64];      // bf16 h rows 0..68, XOR-swizzled (row 69 unused)
  __shared__ float tl2[72 * TLS];  // t rows: [0]=t67 [1..68]=t0..67 [69]=t0 [70]=t68 [71]=t_q
  __shared__ float qsum[4 * 64];   // layer-0 per-wave master-agg partials
  __shared__ float mrow[64];       // final master h (attention input)
  __shared__ float gv[192];        // readout concat [mean|max|master*att]

  const int tid = threadIdx.x;
  const int g = blockIdx.x;
  const int lane = tid & 63;
  const int wv = tid >> 6;
  const int p15 = lane & 15;
  const int qg = lane >> 4;
  const int ec = tid >> 4;        // node-chunk 0..15
  const int f0 = (tid & 15) * 4;  // feature quad

  // h state: NAMED registers only (no arrays -> no scratch)
  f32x4 h0 = {0.f, 0.f, 0.f, 0.f}, h1 = h0, h2 = h0, h3 = h0, h4 = h0, hm = h0;

  // prefetch layer-1 W fragments
  const u16* fb1 = frag + ((size_t)(0 * 4 + wv) * 2 * 64 + lane) * 8;
  short8 b0 = *(const short8*)fb1;
  short8 b1 = *(const short8*)(fb1 + 512);

  // ---- layer 0: t = x @ W_first (exact fp32, K=4) + master-agg partials
  {
    const float* xg = x + (size_t)g * NPG * 4;
    const float w00 = cfW[lane], w01 = cfW[64 + lane];
    const float w02 = cfW[128 + lane], w03 = cfW[192 + lane];
    float qpart = 0.f;
#pragma unroll
    for (int it = 0; it < 18; ++it) {
      const int n = it * 4 + wv;
      if (n < NPG) {
        const f32x4 xv = *(const f32x4*)&xg[n * 4];
        const float t = fmaf(xv[0], w00, fmaf(xv[1], w01, fmaf(xv[2], w02, xv[3] * w03)));
        const int idx = (n == LM) ? 70 : n + 1;
        tl2[idx * TLS + lane] = t;
        if (n == 0) tl2[69 * TLS + lane] = t;
        if (n == 67) tl2[lane] = t;
        qpart += ((n < LM) ? CML : SELFM) * t;
      }
    }
    qsum[wv * 64 + lane] = qpart;
  }
  __syncthreads();
  EPILOGUE(cfb, bns, false, false, true);

  // ---- layers 1..7: t = h @ W via bf16 MFMA; t_q reduced in-wave post-MFMA
#pragma unroll 1
  for (int l = 1; l <= 7; ++l) {
    short8 nb0, nb1;
    if (l < 7) {  // prefetch next layer's fragments
      const u16* fb = frag + ((size_t)(l * 4 + wv) * 2 * 64 + lane) * 8;
      nb0 = *(const short8*)fb;
      nb1 = *(const short8*)(fb + 512);
    }
    {
      const int col = wv * 16 + p15;
      float qacc = 0.f;
#pragma unroll
      for (int mt = 0; mt < 5; ++mt) {
        int row = mt * 16 + p15;
        if (row > LM) row = LM;  // clamp into written hb rows (outputs discarded)
        const int sw = (row & 7) << 3;
        const short8 a0 = *(const short8*)&hb[(row * 64 + qg * 8) ^ sw];
        const short8 a1 = *(const short8*)&hb[(row * 64 + 32 + qg * 8) ^ sw];
        f32x4 acc = {0.f, 0.f, 0.f, 0.f};
        acc = __builtin_amdgcn_mfma_f32_16x16x32_bf16(a0, b0, acc, 0, 0, 0);
        acc = __builtin_amdgcn_mfma_f32_16x16x32_bf16(a1, b1, acc, 0, 0, 0);
        const int rb = mt * 16 + qg * 4;
#pragma unroll
        for (int r = 0; r < 4; ++r) {
          const int rh = rb + r;
          if (rh < NPG) {
            const int idx = (rh == LM) ? 70 : rh + 1;
            tl2[idx * TLS + col] = acc[r];
            if (rh == 0) tl2[69 * TLS + col] = acc[r];
            if (rh == 67) tl2[col] = acc[r];
            qacc += ((rh < LM) ? CML : SELFM) * acc[r];
          }
        }
      }
      // t_q[col] = CML*sum_{n<68} t_n[col] + SELFM*t_68[col]: in-wave reduce
      qacc += __shfl_xor(qacc, 16, 64);
      qacc += __shfl_xor(qacc, 32, 64);
      if (lane < 16) tl2[71 * TLS + col] = qacc;
    }
    if (l < 7) { b0 = nb0; b1 = nb1; }
    __syncthreads();
    if (l < 7) EPILOGUE(cmb + (l - 1) * 64, bns + l * 128, true, false, false);
    else EPILOGUE(clb, (const float*)nullptr, false, true, false);
  }

  // ---- readout: mean/max over landmarks (register h), gated master, fc head
  {
    float* rsum = tl2;  // tl2 is dead: reuse as scratch
    float* rmax = tl2 + 256;
    f32x4 s = {0.f, 0.f, 0.f, 0.f};
    f32x4 m = {-3.402823466e38f, -3.402823466e38f, -3.402823466e38f, -3.402823466e38f};
#pragma unroll
    for (int e = 0; e < 4; ++e) {
      s[e] = h0[e] + h1[e] + h2[e] + h3[e];
      m[e] = fmaxf(fmaxf(h0[e], h1[e]), fmaxf(h2[e], h3[e]));
      if (ec < 4) {
        s[e] += h4[e];
        m[e] = fmaxf(m[e], h4[e]);
      }
      s[e] += __shfl_xor(s[e], 16, 64);
      s[e] += __shfl_xor(s[e], 32, 64);
      m[e] = fmaxf(m[e], __shfl_xor(m[e], 16, 64));
      m[e] = fmaxf(m[e], __shfl_xor(m[e], 32, 64));
    }
    if (lane < 16) {
      *(f32x4*)&rsum[wv * 64 + lane * 4] = s;
      *(f32x4*)&rmax[wv * 64 + lane * 4] = m;
    }
    if (tid < 64) {  // attention gate on master
      float z = ab1[tid];
      for (int k = 0; k < 64; ++k) z += mrow[k] * aW1[k * 64 + tid];
      z = fmaxf(z, 0.f);
      float pr = z * aW2[tid];
#pragma unroll
      for (int off = 32; off > 0; off >>= 1) pr += __shfl_xor(pr, off, 64);
      const float att = 1.f / (1.f + expf(-(pr + ab2[0])));
      gv[128 + tid] = mrow[tid] * att;
    }
    __syncthreads();
    if (tid < 16) {
#pragma unroll
      for (int e = 0; e < 4; ++e) {
        const float S = rsum[f0 + e] + rsum[64 + f0 + e] + rsum[128 + f0 + e] + rsum[192 + f0 + e];
        const float M = fmaxf(fmaxf(rmax[f0 + e], rmax[64 + f0 + e]),
                              fmaxf(rmax[128 + f0 + e], rmax[192 + f0 + e]));
        gv[f0 + e] = S * (1.f / 68.f);
        gv[64 + f0 + e] = M;
      }
    }
    __syncthreads();
    if (tid < 64) {  // fc1 + relu + fc2
      float a1 = f1b[tid];
      for (int i = 0; i < 192; ++i) a1 += gv[i] * f1W[i * 64 + tid];
      const float y = fmaxf(a1, 0.f);
      float po[7];
#pragma unroll
      for (int o = 0; o < 7; ++o) po[o] = y * f2W[tid * 7 + o];
#pragma unroll
      for (int o = 0; o < 7; ++o)
#pragma unroll
        for (int off = 32; off > 0; off >>= 1) po[o] += __shfl_xor(po[o], off, 64);
      if (tid == 0) {
#pragma unroll
        for (int o = 0; o < 7; ++o) out[(size_t)g * 7 + o] = po[o] + f2b[o];
      }
    }
  }
}

extern "C" void kernel_launch(void* const* d_in, const int* in_sizes, int n_in,
                              void* d_out, int out_size, void* d_ws, size_t ws_size,
                              hipStream_t stream) {
  (void)in_sizes; (void)n_in; (void)ws_size;
  const float* x   = (const float*)d_in[0];
  const float* cfW = (const float*)d_in[4];
  const float* cfb = (const float*)d_in[5];
  const float* cmW = (const float*)d_in[6];
  const float* cmb = (const float*)d_in[7];
  const float* clW = (const float*)d_in[8];
  const float* clb = (const float*)d_in[9];
  const float* bng = (const float*)d_in[10];
  const float* bnb = (const float*)d_in[11];
  const float* bnm = (const float*)d_in[12];
  const float* bnv = (const float*)d_in[13];
  const float* aW1 = (const float*)d_in[14];
  const float* ab1 = (const float*)d_in[15];
  const float* aW2 = (const float*)d_in[16];
  const float* ab2 = (const float*)d_in[17];
  const float* f1W = (const float*)d_in[18];
  const float* f1b = (const float*)d_in[19];
  const float* f2W = (const float*)d_in[20];
  const float* f2b = (const float*)d_in[21];

  u16* frag = (u16*)d_ws;                      // 57344 B
  float* bns = (float*)((char*)d_ws + 57344);  // 7*128 floats
  const int ngraphs = out_size / 7;

  prep<<<dim3(16), dim3(256), 0, stream>>>(cmW, clW, bng, bnb, bnm, bnv, frag, bns);
  gcn_fused<<<dim3(ngraphs), dim3(256), 0, stream>>>(
      x, cfW, cfb, cmb, clb, aW1, ab1, aW2, ab2, f1W, f1b, f2W, f2b,
      frag, bns, (float*)d_out);
}

// Round 4
// 217.245 us; speedup vs baseline: 3.9345x; 1.5142x over previous
//
#include <hip/hip_runtime.h>

typedef float f32x4 __attribute__((ext_vector_type(4)));
typedef short short8 __attribute__((ext_vector_type(8)));
typedef unsigned int u32;
typedef unsigned short u16;
typedef u32 u32x2 __attribute__((ext_vector_type(2)));

#define NPG 69   // nodes per graph
#define LM 68    // landmark count / master index
#define TLS 68   // tl2 row stride (words); 4*68 % 32 = 16 -> 2-way on MFMA col-writes
#define CLL 0.25f                     // landmark<-landmark/self coeff
#define CML 0.06019292654288460f      // 0.5/sqrt(69)
#define SELFM 0.014492753623188406f   // 1/69

__device__ __forceinline__ u16 f2bf(float x) {
  u32 b = __float_as_uint(x);
  return (u16)((b + 0x7FFFu + ((b >> 16) & 1u)) >> 16);
}

__device__ __forceinline__ void store_hb(u16* hb, int nrow, int fq, f32x4 v) {
  const int base = (nrow * 64 + fq) ^ ((nrow & 7) << 3);  // 16B-block XOR swizzle
  u32x2 w;
  w.x = (u32)f2bf(v[0]) | ((u32)f2bf(v[1]) << 16);
  w.y = (u32)f2bf(v[2]) | ((u32)f2bf(v[3]) << 16);
  *(u32x2*)&hb[base] = w;
}

// prep: (a) swizzle 7 HIDxHID weight mats into bf16 MFMA B-fragments;
//       (b) fold BN into per-layer affine sc/sh.
__global__ void prep(const float* __restrict__ midW, const float* __restrict__ lastW,
                     const float* __restrict__ bng, const float* __restrict__ bnb,
                     const float* __restrict__ bnm, const float* __restrict__ bnv,
                     u16* __restrict__ frag, float* __restrict__ bns) {
  const int t0 = blockIdx.x * blockDim.x + threadIdx.x;
  for (int u = t0; u < 7 * 4 * 2 * 64; u += gridDim.x * blockDim.x) {
    const int lane = u & 63;
    const int t = u >> 6;
    const int ks = t & 1;
    const int nt = (t >> 1) & 3;
    const int l = t >> 3;  // 0..6 -> layers 1..7
    const float* W = (l < 6) ? (midW + l * 4096) : lastW;
    const int col = nt * 16 + (lane & 15);
    const int kb = ks * 32 + (lane >> 4) * 8;
    u16* dst = frag + (size_t)u * 8;
#pragma unroll
    for (int j = 0; j < 8; ++j) dst[j] = f2bf(W[(kb + j) * 64 + col]);
  }
  for (int u = t0; u < 7 * 64; u += gridDim.x * blockDim.x) {
    const int l = u >> 6, f = u & 63;
    const float sc = (float)((double)bng[l * 64 + f] / sqrt((double)bnv[l * 64 + f] + 1e-5));
    bns[l * 128 + f] = sc;
    bns[l * 128 + 64 + f] = bnb[l * 64 + f] - bnm[l * 64 + f] * sc;
  }
}

// ---- epilogue macros: ALL state in named registers, ALL indices compile-time.
#define EPI_CHUNK(IT, H, RESID, LAST)                                        \
  do {                                                                       \
    const int n_ = (IT) * 16 + ec;                                           \
    const f32x4 ta_ = *(const f32x4*)&tl2[n_ * TLS + f0];                    \
    const f32x4 ts_ = *(const f32x4*)&tl2[(n_ + 1) * TLS + f0];              \
    const f32x4 tb_ = *(const f32x4*)&tl2[(n_ + 2) * TLS + f0];              \
    f32x4 o_;                                                                \
    _Pragma("unroll") for (int e = 0; e < 4; ++e) {                          \
      float v_ = CLL * (ta_[e] + ts_[e] + tb_[e]) + CML * tm_[e] + bias_[e]; \
      v_ = fmaxf(v_, 0.f);                                                   \
      v_ = v_ * sc_[e] + sh_[e];                                             \
      if (RESID) v_ += H[e];                                                 \
      o_[e] = v_;                                                            \
    }                                                                        \
    H = o_;                                                                  \
    if (!(LAST)) store_hb(hb, n_, f0, o_);                                   \
  } while (0)

#define EPILOGUE(BIASP, BNSP, RESID, LAST, L0)                               \
  do {                                                                       \
    const f32x4 bias_ = *(const f32x4*)&(BIASP)[f0];                         \
    f32x4 sc_, sh_;                                                          \
    const float* bnsp_ = (BNSP);                                             \
    if (bnsp_) {                                                             \
      sc_ = *(const f32x4*)&bnsp_[f0];                                       \
      sh_ = *(const f32x4*)&bnsp_[64 + f0];                                  \
    } else {                                                                 \
      sc_ = (f32x4){1.f, 1.f, 1.f, 1.f};                                     \
      sh_ = (f32x4){0.f, 0.f, 0.f, 0.f};                                     \
    }                                                                        \
    const f32x4 tm_ = *(const f32x4*)&tl2[70 * TLS + f0];                    \
    EPI_CHUNK(0, h0, RESID, LAST);                                           \
    EPI_CHUNK(1, h1, RESID, LAST);                                           \
    EPI_CHUNK(2, h2, RESID, LAST);                                           \
    EPI_CHUNK(3, h3, RESID, LAST);                                           \
    if (ec < 4) EPI_CHUNK(4, h4, RESID, LAST);                               \
    if (tid < 16) {                                                          \
      f32x4 zm_;                                                             \
      if (L0) {                                                              \
        _Pragma("unroll") for (int e = 0; e < 4; ++e) zm_[e] =               \
            qsum[f0 + e] + qsum[64 + f0 + e] + qsum[128 + f0 + e] +          \
            qsum[192 + f0 + e];                                              \
      } else {                                                               \
        zm_ = *(const f32x4*)&tl2[71 * TLS + f0];                            \
      }                                                                      \
      f32x4 om_;                                                             \
      _Pragma("unroll") for (int e = 0; e < 4; ++e) {                        \
        float v_ = zm_[e] + bias_[e];                                        \
        v_ = fmaxf(v_, 0.f);                                                 \
        v_ = v_ * sc_[e] + sh_[e];                                           \
        if (RESID) v_ += hm[e];                                              \
        om_[e] = v_;                                                         \
      }                                                                      \
      hm = om_;                                                              \
      if (!(LAST)) store_hb(hb, LM, f0, om_);                                \
      else *(f32x4*)&mrow[f0] = om_;                                         \
    }                                                                        \
    __syncthreads();                                                         \
  } while (0)

__launch_bounds__(256)
__global__ void gcn_fused(
    const float* __restrict__ x,
    const float* __restrict__ cfW, const float* __restrict__ cfb,
    const float* __restrict__ cmb, const float* __restrict__ clb,
    const float* __restrict__ aW1, const float* __restrict__ ab1,
    const float* __restrict__ aW2, const float* __restrict__ ab2,
    const float* __restrict__ f1W, const float* __restrict__ f1b,
    const float* __restrict__ f2W, const float* __restrict__ f2b,
    const u16* __restrict__ frag, const float* __restrict__ bns,
    float* __restrict__ out) {
  // LDS: 8960 + 19584 + 1024 + 256 + 768 = 30592 B
  __shared__ u16 hb[70 * 64];      // bf16 h rows 0..68, XOR-swizzled (row 69 unused)
  __shared__ float tl2[72 * TLS];  // t rows: [0]=t67 [1..68]=t0..67 [69]=t0 [70]=t68 [71]=t_q
  __shared__ float qsum[4 * 64];   // layer-0 per-wave master-agg partials
  __shared__ float mrow[64];       // final master h (attention input)
  __shared__ float gv[192];        // readout concat [mean|max|master*att]

  const int tid = threadIdx.x;
  const int g = blockIdx.x;
  const int lane = tid & 63;
  const int wv = tid >> 6;
  const int p15 = lane & 15;
  const int qg = lane >> 4;
  const int ec = tid >> 4;        // node-chunk 0..15
  const int f0 = (tid & 15) * 4;  // feature quad

  // h state: NAMED registers only (no arrays -> no scratch)
  f32x4 h0 = {0.f, 0.f, 0.f, 0.f}, h1 = h0, h2 = h0, h3 = h0, h4 = h0, hm = h0;

  // prefetch layer-1 W fragments
  const u16* fb1 = frag + ((size_t)(0 * 4 + wv) * 2 * 64 + lane) * 8;
  short8 b0 = *(const short8*)fb1;
  short8 b1 = *(const short8*)(fb1 + 512);

  // ---- layer 0: t = x @ W_first (exact fp32, K=4) + master-agg partials
  {
    const float* xg = x + (size_t)g * NPG * 4;
    const float w00 = cfW[lane], w01 = cfW[64 + lane];
    const float w02 = cfW[128 + lane], w03 = cfW[192 + lane];
    float qpart = 0.f;
#pragma unroll
    for (int it = 0; it < 18; ++it) {
      const int n = it * 4 + wv;
      if (n < NPG) {
        const f32x4 xv = *(const f32x4*)&xg[n * 4];
        const float t = fmaf(xv[0], w00, fmaf(xv[1], w01, fmaf(xv[2], w02, xv[3] * w03)));
        const int idx = (n == LM) ? 70 : n + 1;
        tl2[idx * TLS + lane] = t;
        if (n == 0) tl2[69 * TLS + lane] = t;
        if (n == 67) tl2[lane] = t;
        qpart += ((n < LM) ? CML : SELFM) * t;
      }
    }
    qsum[wv * 64 + lane] = qpart;
  }
  __syncthreads();
  EPILOGUE(cfb, bns, false, false, true);

  // ---- layers 1..7: t = h @ W via bf16 MFMA; t_q reduced in-wave post-MFMA
#pragma unroll 1
  for (int l = 1; l <= 7; ++l) {
    short8 nb0, nb1;
    if (l < 7) {  // prefetch next layer's fragments
      const u16* fb = frag + ((size_t)(l * 4 + wv) * 2 * 64 + lane) * 8;
      nb0 = *(const short8*)fb;
      nb1 = *(const short8*)(fb + 512);
    }
    {
      const int col = wv * 16 + p15;
      float qacc = 0.f;
#pragma unroll
      for (int mt = 0; mt < 5; ++mt) {
        int row = mt * 16 + p15;
        if (row > LM) row = LM;  // clamp into written hb rows (outputs discarded)
        const int sw = (row & 7) << 3;
        const short8 a0 = *(const short8*)&hb[(row * 64 + qg * 8) ^ sw];
        const short8 a1 = *(const short8*)&hb[(row * 64 + 32 + qg * 8) ^ sw];
        f32x4 acc = {0.f, 0.f, 0.f, 0.f};
        acc = __builtin_amdgcn_mfma_f32_16x16x32_bf16(a0, b0, acc, 0, 0, 0);
        acc = __builtin_amdgcn_mfma_f32_16x16x32_bf16(a1, b1, acc, 0, 0, 0);
        const int rb = mt * 16 + qg * 4;
#pragma unroll
        for (int r = 0; r < 4; ++r) {
          const int rh = rb + r;
          if (rh < NPG) {
            const int idx = (rh == LM) ? 70 : rh + 1;
            tl2[idx * TLS + col] = acc[r];
            if (rh == 0) tl2[69 * TLS + col] = acc[r];
            if (rh == 67) tl2[col] = acc[r];
            qacc += ((rh < LM) ? CML : SELFM) * acc[r];
          }
        }
      }
      // t_q[col] = CML*sum_{n<68} t_n[col] + SELFM*t_68[col]: in-wave reduce
      qacc += __shfl_xor(qacc, 16, 64);
      qacc += __shfl_xor(qacc, 32, 64);
      if (lane < 16) tl2[71 * TLS + col] = qacc;
    }
    if (l < 7) { b0 = nb0; b1 = nb1; }
    __syncthreads();
    if (l < 7) EPILOGUE(cmb + (l - 1) * 64, bns + l * 128, true, false, false);
    else EPILOGUE(clb, (const float*)nullptr, false, true, false);
  }

  // ---- readout: mean/max over landmarks (register h), gated master, fc head
  {
    float* rsum = tl2;  // tl2 is dead: reuse as scratch
    float* rmax = tl2 + 256;
    f32x4 s = {0.f, 0.f, 0.f, 0.f};
    f32x4 m = {-3.402823466e38f, -3.402823466e38f, -3.402823466e38f, -3.402823466e38f};
#pragma unroll
    for (int e = 0; e < 4; ++e) {
      s[e] = h0[e] + h1[e] + h2[e] + h3[e];
      m[e] = fmaxf(fmaxf(h0[e], h1[e]), fmaxf(h2[e], h3[e]));
      if (ec < 4) {
        s[e] += h4[e];
        m[e] = fmaxf(m[e], h4[e]);
      }
      s[e] += __shfl_xor(s[e], 16, 64);
      s[e] += __shfl_xor(s[e], 32, 64);
      m[e] = fmaxf(m[e], __shfl_xor(m[e], 16, 64));
      m[e] = fmaxf(m[e], __shfl_xor(m[e], 32, 64));
    }
    if (lane < 16) {
      *(f32x4*)&rsum[wv * 64 + lane * 4] = s;
      *(f32x4*)&rmax[wv * 64 + lane * 4] = m;
    }
    if (tid < 64) {  // attention gate on master
      float z = ab1[tid];
      for (int k = 0; k < 64; ++k) z += mrow[k] * aW1[k * 64 + tid];
      z = fmaxf(z, 0.f);
      float pr = z * aW2[tid];
#pragma unroll
      for (int off = 32; off > 0; off >>= 1) pr += __shfl_xor(pr, off, 64);
      const float att = 1.f / (1.f + expf(-(pr + ab2[0])));
      gv[128 + tid] = mrow[tid] * att;
    }
    __syncthreads();
    if (tid < 16) {
#pragma unroll
      for (int e = 0; e < 4; ++e) {
        const float S = rsum[f0 + e] + rsum[64 + f0 + e] + rsum[128 + f0 + e] + rsum[192 + f0 + e];
        const float M = fmaxf(fmaxf(rmax[f0 + e], rmax[64 + f0 + e]),
                              fmaxf(rmax[128 + f0 + e], rmax[192 + f0 + e]));
        gv[f0 + e] = S * (1.f / 68.f);
        gv[64 + f0 + e] = M;
      }
    }
    __syncthreads();
    if (tid < 64) {  // fc1 + relu + fc2
      float a1 = f1b[tid];
      for (int i = 0; i < 192; ++i) a1 += gv[i] * f1W[i * 64 + tid];
      const float y = fmaxf(a1, 0.f);
      float po[7];
#pragma unroll
      for (int o = 0; o < 7; ++o) po[o] = y * f2W[tid * 7 + o];
#pragma unroll
      for (int o = 0; o < 7; ++o)
#pragma unroll
        for (int off = 32; off > 0; off >>= 1) po[o] += __shfl_xor(po[o], off, 64);
      if (tid == 0) {
#pragma unroll
        for (int o = 0; o < 7; ++o) out[(size_t)g * 7 + o] = po[o] + f2b[o];
      }
    }
  }
}

extern "C" void kernel_launch(void* const* d_in, const int* in_sizes, int n_in,
                              void* d_out, int out_size, void* d_ws, size_t ws_size,
                              hipStream_t stream) {
  (void)in_sizes; (void)n_in; (void)ws_size;
  const float* x   = (const float*)d_in[0];
  const float* cfW = (const float*)d_in[4];
  const float* cfb = (const float*)d_in[5];
  const float* cmW = (const float*)d_in[6];
  const float* cmb = (const float*)d_in[7];
  const float* clW = (const float*)d_in[8];
  const float* clb = (const float*)d_in[9];
  const float* bng = (const float*)d_in[10];
  const float* bnb = (const float*)d_in[11];
  const float* bnm = (const float*)d_in[12];
  const float* bnv = (const float*)d_in[13];
  const float* aW1 = (const float*)d_in[14];
  const float* ab1 = (const float*)d_in[15];
  const float* aW2 = (const float*)d_in[16];
  const float* ab2 = (const float*)d_in[17];
  const float* f1W = (const float*)d_in[18];
  const float* f1b = (const float*)d_in[19];
  const float* f2W = (const float*)d_in[20];
  const float* f2b = (const float*)d_in[21];

  u16* frag = (u16*)d_ws;                      // 57344 B
  float* bns = (float*)((char*)d_ws + 57344);  // 7*128 floats
  const int ngraphs = out_size / 7;

  prep<<<dim3(16), dim3(256), 0, stream>>>(cmW, clW, bng, bnb, bnm, bnv, frag, bns);
  gcn_fused<<<dim3(ngraphs), dim3(256), 0, stream>>>(
      x, cfW, cfb, cmb, clb, aW1, ab1, aW2, ab2, f1W, f1b, f2W, f2b,
      frag, bns, (float*)d_out);
}

// Round 5
// 154.725 us; speedup vs baseline: 5.5243x; 1.4041x over previous
//
#include <hip/hip_runtime.h>

typedef float f32x4 __attribute__((ext_vector_type(4)));
typedef short short8 __attribute__((ext_vector_type(8)));
typedef unsigned int u32;
typedef unsigned short u16;

#define CLL 0.25f                     // landmark self/neighbor coeff (deg=4)
#define CML 0.06019292654288460f      // 0.5/sqrt(69)
#define SELFM 0.014492753623188406f   // 1/69

__device__ __forceinline__ u16 f2bf(float x) {
  u32 b = __float_as_uint(x);
  return (u16)((b + 0x7FFFu + ((b >> 16) & 1u)) >> 16);
}

__device__ __forceinline__ u32 cvtpk(float a, float b) {
  u32 r;
  asm("v_cvt_pk_bf16_f32 %0, %1, %2" : "=v"(r) : "v"(a), "v"(b));
  return r;
}

// prep: (a) swizzle 7 HIDxHID weight mats into bf16 MFMA B-fragments;
//       (b) fold BN into per-layer affine sc/sh.
__global__ void prep(const float* __restrict__ midW, const float* __restrict__ lastW,
                     const float* __restrict__ bng, const float* __restrict__ bnb,
                     const float* __restrict__ bnm, const float* __restrict__ bnv,
                     u16* __restrict__ frag, float* __restrict__ bns) {
  const int t0 = blockIdx.x * blockDim.x + threadIdx.x;
  for (int u = t0; u < 7 * 4 * 2 * 64; u += gridDim.x * blockDim.x) {
    const int lane = u & 63;
    const int t = u >> 6;
    const int ks = t & 1;
    const int nt = (t >> 1) & 3;
    const int l = t >> 3;  // 0..6 -> layers 1..7
    const float* W = (l < 6) ? (midW + l * 4096) : lastW;
    const int col = nt * 16 + (lane & 15);
    const int kb = ks * 32 + (lane >> 4) * 8;
    u16* dst = frag + (size_t)u * 8;
#pragma unroll
    for (int j = 0; j < 8; ++j) dst[j] = f2bf(W[(kb + j) * 64 + col]);
  }
  for (int u = t0; u < 7 * 64; u += gridDim.x * blockDim.x) {
    const int l = u >> 6, f = u & 63;
    const float sc = (float)((double)bng[l * 64 + f] / sqrt((double)bnv[l * 64 + f] + 1e-5));
    bns[l * 128 + f] = sc;
    bns[l * 128 + 64 + f] = bnb[l * 64 + f] - bnm[l * 64 + f] * sc;
  }
}

#define SUM4(V) ((V)[0] + (V)[1] + (V)[2] + (V)[3])
#define MAX4(V) fmaxf(fmaxf((V)[0], (V)[1]), fmaxf((V)[2], (V)[3]))

// write address (elems) for node n=16*MT+4*qg+R, col c, XOR-swizzled
#define WADDR(MT, R) ((16 * (MT) + 4 * qg + (R)) * 64 + (cq ^ ((R) << 3)))

// ring stencil for one 4-node run; H updated in place. All indices compile-time.
#define STEP(MT, T, TPM1, TNP1, H, RESID)                              \
  {                                                                    \
    const float sp = (qg == 3) ? TPM1[3] : T[3];                       \
    const float pv = __shfl(sp, (lane + 48) & 63, 64);                 \
    const float sn = (qg == 0) ? TNP1[0] : T[0];                       \
    const float nv = __shfl(sn, (lane + 16) & 63, 64);                 \
    const float ta0 = ((MT) == 0 && qg == 0) ? t4[3] : pv;             \
    const float tb3 = ((MT) == 4 && qg == 0) ? t0[0] : nv;             \
    float o0 = fmaf(CLL, ta0 + T[0] + T[1], cmt);                      \
    float o1 = fmaf(CLL, T[0] + T[1] + T[2], cmt);                     \
    float o2 = fmaf(CLL, T[1] + T[2] + T[3], cmt);                     \
    float o3 = fmaf(CLL, T[2] + T[3] + tb3, cmt);                      \
    o0 = fmaf(fmaxf(o0, 0.f), sc, sh);                                 \
    o1 = fmaf(fmaxf(o1, 0.f), sc, sh);                                 \
    o2 = fmaf(fmaxf(o2, 0.f), sc, sh);                                 \
    o3 = fmaf(fmaxf(o3, 0.f), sc, sh);                                 \
    if (RESID) { o0 += H[0]; o1 += H[1]; o2 += H[2]; o3 += H[3]; }     \
    H[0] = o0; H[1] = o1; H[2] = o2; H[3] = o3;                        \
  }

#define WPAIR(HW, MT, H)                                               \
  {                                                                    \
    const u32 pa = cvtpk(H[0], H[1]);                                  \
    const u32 pb = cvtpk(H[2], H[3]);                                  \
    (HW)[WADDR(MT, 0)] = (u16)pa;                                      \
    (HW)[WADDR(MT, 1)] = (u16)(pa >> 16);                              \
    (HW)[WADDR(MT, 2)] = (u16)pb;                                      \
    (HW)[WADDR(MT, 3)] = (u16)(pb >> 16);                              \
  }

// epilogue: master agg + stencil + bn/relu/resid in registers, then bf16 writes
#define EPILOG(RESID, WRITE, HBW)                                      \
  {                                                                    \
    float S = SUM4(t0) + SUM4(t1) + SUM4(t2) + SUM4(t3) + SUM4(t4);    \
    if (qg == 1) S -= t4[0]; /* exclude master t; pad rows are 0 */    \
    S += __shfl_xor(S, 16, 64);                                        \
    S += __shfl_xor(S, 32, 64);                                        \
    const float t68b = __shfl(t4[0], 16 + p15, 64);                    \
    const float cmt = fmaf(CML, t68b, bias);                           \
    float mv = fmaxf(fmaf(CML, S, fmaf(SELFM, t68b, bias)), 0.f);      \
    mv = fmaf(mv, sc, sh);                                             \
    if (RESID) mv += h4[0];                                            \
    STEP(0, t0, t4, t1, h0, RESID)                                     \
    STEP(1, t1, t0, t2, h1, RESID)                                     \
    STEP(2, t2, t1, t3, h2, RESID)                                     \
    STEP(3, t3, t2, t4, h3, RESID)                                     \
    STEP(4, t4, t3, t0, h4, RESID)                                     \
    if (qg == 1) h4[0] = mv; /* master h lives in slot [4][0] */       \
    if (WRITE) {                                                       \
      u16* hw_ = (HBW);                                                \
      WPAIR(hw_, 0, h0)                                                \
      WPAIR(hw_, 1, h1)                                                \
      WPAIR(hw_, 2, h2)                                                \
      WPAIR(hw_, 3, h3)                                                \
      if (qg == 0) { WPAIR(hw_, 4, h4) }                               \
      else if (qg == 1) hw_[68 * 64 + (c ^ 32)] = (u16)cvtpk(h4[0], h4[0]); \
    }                                                                  \
  }

#define MP(HR, MT, T)                                                  \
  {                                                                    \
    const short8 a0 = *(const short8*)&(HR)[(MT) * 1024 + ra0];        \
    const short8 a1 = *(const short8*)&(HR)[(MT) * 1024 + ra1];        \
    f32x4 acc = {0.f, 0.f, 0.f, 0.f};                                  \
    acc = __builtin_amdgcn_mfma_f32_16x16x32_bf16(a0, b0, acc, 0, 0, 0); \
    acc = __builtin_amdgcn_mfma_f32_16x16x32_bf16(a1, b1, acc, 0, 0, 0); \
    T = acc;                                                           \
  }

__launch_bounds__(256)
__global__ void gcn_fused(
    const float* __restrict__ x,
    const float* __restrict__ cfW, const float* __restrict__ cfb,
    const float* __restrict__ cmb, const float* __restrict__ clb,
    const float* __restrict__ aW1, const float* __restrict__ ab1,
    const float* __restrict__ aW2, const float* __restrict__ ab2,
    const float* __restrict__ f1W, const float* __restrict__ f1b,
    const float* __restrict__ f2W, const float* __restrict__ f2b,
    const u16* __restrict__ frag, const float* __restrict__ bns,
    float* __restrict__ out) {
  // LDS: 20480 + 1280 + 256 + 768 + 1024 = 23808 B -> 6 blocks/CU by LDS
  __shared__ u16 hb[2][80 * 64];  // bf16 h double-buffer, rows 69..79 stay 0
  __shared__ float xl4[80 * 4];   // staged x, rows 69..79 = 0
  __shared__ float mrow[64];      // final master h
  __shared__ float gv[192];       // readout concat [mean|max|master*att]
  __shared__ float part[256];     // cross-wave partial buffer (att / fc1)

  const int tid = threadIdx.x;
  const int g = blockIdx.x;
  const int lane = tid & 63;
  const int wv = tid >> 6;
  const int p15 = lane & 15;
  const int qg = lane >> 4;
  const int c = wv * 16 + p15;            // this thread's feature column
  const int cq = c ^ ((qg & 1) << 5);     // write-swizzle base
  const int rsw = (p15 & 7) << 3;
  const int ra0 = (p15 * 64 + qg * 8) ^ rsw;        // A-frag kg=0 base
  const int ra1 = (p15 * 64 + 32 + qg * 8) ^ rsw;   // A-frag kg=1 base

  // zero both hb buffers (pad rows must stay 0); stage x
  for (int i = tid; i < 5120; i += 256) ((u32*)hb)[i] = 0u;
  if (tid < 69)
    *(f32x4*)&xl4[tid * 4] = *(const f32x4*)&x[((size_t)g * 69 + tid) * 4];
  else if (tid < 80)
    *(f32x4*)&xl4[tid * 4] = (f32x4){0.f, 0.f, 0.f, 0.f};

  // prefetch layer-1 B fragments
  const u16* fb = frag + ((size_t)(0 * 4 + wv) * 2 * 64 + lane) * 8;
  short8 b0 = *(const short8*)fb;
  short8 b1 = *(const short8*)(fb + 512);

  f32x4 t0, t1, t2, t3, t4;
  f32x4 h0, h1, h2, h3, h4;

  __syncthreads();

  // ---- layer 0: t = x @ W_first (exact fp32, K=4), nodes in MFMA layout
  {
    const float w0 = cfW[c], w1 = cfW[64 + c], w2 = cfW[128 + c], w3 = cfW[192 + c];
#define L0T(MT, T)                                                     \
    { _Pragma("unroll") for (int r = 0; r < 4; ++r) {                  \
        const f32x4 xv = *(const f32x4*)&xl4[(16 * (MT) + 4 * qg + r) * 4]; \
        T[r] = fmaf(xv[0], w0, fmaf(xv[1], w1, fmaf(xv[2], w2, xv[3] * w3))); } }
    L0T(0, t0) L0T(1, t1) L0T(2, t2) L0T(3, t3) L0T(4, t4)
#undef L0T
  }
  {
    const float bias = cfb[c];
    const float sc = bns[c], sh = bns[64 + c];
    EPILOG(false, true, &hb[0][0])
  }
  __syncthreads();

  // ---- layers 1..6: MFMA + register epilogue (bn + residual)
  for (int l = 1; l <= 6; ++l) {
    const u16* fbn = frag + ((size_t)(l * 4 + wv) * 2 * 64 + lane) * 8;
    const short8 nb0 = *(const short8*)fbn;
    const short8 nb1 = *(const short8*)(fbn + 512);
    const u16* hr = &hb[(l + 1) & 1][0];
    MP(hr, 0, t0) MP(hr, 1, t1) MP(hr, 2, t2) MP(hr, 3, t3) MP(hr, 4, t4)
    b0 = nb0;
    b1 = nb1;
    const float bias = cmb[(l - 1) * 64 + c];
    const float sc = bns[l * 128 + c], sh = bns[l * 128 + 64 + c];
    EPILOG(true, true, &hb[l & 1][0])
    __syncthreads();
  }

  // ---- layer 7: MFMA + epilogue (no bn, no residual, no hb write)
  {
    const u16* hr = &hb[0][0];
    MP(hr, 0, t0) MP(hr, 1, t1) MP(hr, 2, t2) MP(hr, 3, t3) MP(hr, 4, t4)
    const float bias = clb[c];
    const float sc = 1.f, sh = 0.f;
    EPILOG(false, false, (u16*)nullptr)
  }

  // ---- readout: per-col landmark mean/max from registers
  {
    float s = SUM4(h0) + SUM4(h1) + SUM4(h2) + SUM4(h3);
    float mx = fmaxf(fmaxf(MAX4(h0), MAX4(h1)), fmaxf(MAX4(h2), MAX4(h3)));
    if (qg == 0) {  // only qg==0's mt=4 run (nodes 64..67) is valid landmarks
      s += SUM4(h4);
      mx = fmaxf(mx, MAX4(h4));
    }
    s += __shfl_xor(s, 16, 64);
    s += __shfl_xor(s, 32, 64);
    mx = fmaxf(mx, __shfl_xor(mx, 16, 64));
    mx = fmaxf(mx, __shfl_xor(mx, 32, 64));
    if (qg == 0) {
      gv[c] = s * (1.f / 68.f);
      gv[64 + c] = mx;
    }
    if (qg == 1) mrow[c] = h4[0];
  }
  __syncthreads();

  // ---- attention gate (distributed over all 4 waves)
  {
    float z = 0.f;
#pragma unroll
    for (int k = 0; k < 16; ++k)
      z = fmaf(mrow[wv * 16 + k], aW1[(wv * 16 + k) * 64 + lane], z);
    part[wv * 64 + lane] = z;
  }
  __syncthreads();
  if (tid < 64) {
    float z = part[tid] + part[64 + tid] + part[128 + tid] + part[192 + tid] + ab1[tid];
    z = fmaxf(z, 0.f);
    float pr = z * aW2[tid];
#pragma unroll
    for (int off = 32; off > 0; off >>= 1) pr += __shfl_xor(pr, off, 64);
    const float att = 1.f / (1.f + expf(-(pr + ab2[0])));
    gv[128 + tid] = mrow[tid] * att;
  }
  __syncthreads();

  // ---- fc1 partials (distributed over all 4 waves)
  {
    float a = 0.f;
#pragma unroll
    for (int i = 0; i < 48; ++i)
      a = fmaf(gv[wv * 48 + i], f1W[(wv * 48 + i) * 64 + lane], a);
    part[wv * 64 + lane] = a;
  }
  __syncthreads();
  if (tid < 64) {
    float a = part[tid] + part[64 + tid] + part[128 + tid] + part[192 + tid] + f1b[tid];
    const float y = fmaxf(a, 0.f);
    float po[7];
#pragma unroll
    for (int o = 0; o < 7; ++o) po[o] = y * f2W[tid * 7 + o];
#pragma unroll
    for (int o = 0; o < 7; ++o)
#pragma unroll
      for (int off = 32; off > 0; off >>= 1) po[o] += __shfl_xor(po[o], off, 64);
    if (tid == 0) {
#pragma unroll
      for (int o = 0; o < 7; ++o) out[(size_t)g * 7 + o] = po[o] + f2b[o];
    }
  }
}

extern "C" void kernel_launch(void* const* d_in, const int* in_sizes, int n_in,
                              void* d_out, int out_size, void* d_ws, size_t ws_size,
                              hipStream_t stream) {
  (void)in_sizes; (void)n_in; (void)ws_size;
  const float* x   = (const float*)d_in[0];
  const float* cfW = (const float*)d_in[4];
  const float* cfb = (const float*)d_in[5];
  const float* cmW = (const float*)d_in[6];
  const float* cmb = (const float*)d_in[7];
  const float* clW = (const float*)d_in[8];
  const float* clb = (const float*)d_in[9];
  const float* bng = (const float*)d_in[10];
  const float* bnb = (const float*)d_in[11];
  const float* bnm = (const float*)d_in[12];
  const float* bnv = (const float*)d_in[13];
  const float* aW1 = (const float*)d_in[14];
  const float* ab1 = (const float*)d_in[15];
  const float* aW2 = (const float*)d_in[16];
  const float* ab2 = (const float*)d_in[17];
  const float* f1W = (const float*)d_in[18];
  const float* f1b = (const float*)d_in[19];
  const float* f2W = (const float*)d_in[20];
  const float* f2b = (const float*)d_in[21];

  u16* frag = (u16*)d_ws;                      // 57344 B
  float* bns = (float*)((char*)d_ws + 57344);  // 7*128 floats
  const int ngraphs = out_size / 7;

  prep<<<dim3(16), dim3(256), 0, stream>>>(cmW, clW, bng, bnb, bnm, bnv, frag, bns);
  gcn_fused<<<dim3(ngraphs), dim3(256), 0, stream>>>(
      x, cfW, cfb, cmb, clb, aW1, ab1, aW2, ab2, f1W, f1b, f2W, f2b,
      frag, bns, (float*)d_out);
}

// Round 6
// 153.821 us; speedup vs baseline: 5.5567x; 1.0059x over previous
//
#include <hip/hip_runtime.h>

typedef float f32x4 __attribute__((ext_vector_type(4)));
typedef short short8 __attribute__((ext_vector_type(8)));
typedef unsigned int u32;
typedef unsigned short u16;

#define CLL 0.25f                     // landmark self/neighbor coeff (deg=4)
#define CML 0.06019292654288460f      // 0.5/sqrt(69)
#define SELFM 0.014492753623188406f   // 1/69

__device__ __forceinline__ u16 f2bf(float x) {
  u32 b = __float_as_uint(x);
  return (u16)((b + 0x7FFFu + ((b >> 16) & 1u)) >> 16);
}

__device__ __forceinline__ u32 cvtpk(float a, float b) {
  u32 r;
  asm("v_cvt_pk_bf16_f32 %0, %1, %2" : "=v"(r) : "v"(a), "v"(b));
  return r;
}

// prep: (a) swizzle 7 HIDxHID weight mats into bf16 MFMA B-fragments;
//       (b) fold BN into per-layer affine sc/sh.
__global__ void prep(const float* __restrict__ midW, const float* __restrict__ lastW,
                     const float* __restrict__ bng, const float* __restrict__ bnb,
                     const float* __restrict__ bnm, const float* __restrict__ bnv,
                     u16* __restrict__ frag, float* __restrict__ bns) {
  const int t0 = blockIdx.x * blockDim.x + threadIdx.x;
  for (int u = t0; u < 7 * 4 * 2 * 64; u += gridDim.x * blockDim.x) {
    const int lane = u & 63;
    const int t = u >> 6;
    const int ks = t & 1;
    const int nt = (t >> 1) & 3;
    const int l = t >> 3;  // 0..6 -> layers 1..7
    const float* W = (l < 6) ? (midW + l * 4096) : lastW;
    const int col = nt * 16 + (lane & 15);
    const int kb = ks * 32 + (lane >> 4) * 8;
    u16* dst = frag + (size_t)u * 8;
#pragma unroll
    for (int j = 0; j < 8; ++j) dst[j] = f2bf(W[(kb + j) * 64 + col]);
  }
  for (int u = t0; u < 7 * 64; u += gridDim.x * blockDim.x) {
    const int l = u >> 6, f = u & 63;
    const float sc = (float)((double)bng[l * 64 + f] / sqrt((double)bnv[l * 64 + f] + 1e-5));
    bns[l * 128 + f] = sc;
    bns[l * 128 + 64 + f] = bnb[l * 64 + f] - bnm[l * 64 + f] * sc;
  }
}

#define SUM4(V) ((V)[0] + (V)[1] + (V)[2] + (V)[3])
#define MAX4(V) fmaxf(fmaxf((V)[0], (V)[1]), fmaxf((V)[2], (V)[3]))

// write address (elems) for node n=16*MT+4*qg+R, col c, XOR-swizzled
#define WADDR(MT, R) ((16 * (MT) + 4 * qg + (R)) * 64 + (cq ^ ((R) << 3)))

// ring stencil for one 4-node run; H updated in place. All indices compile-time.
#define STEP(MT, T, TPM1, TNP1, H, RESID)                              \
  {                                                                    \
    const float sp = (qg == 3) ? TPM1[3] : T[3];                       \
    const float pv = __shfl(sp, (lane + 48) & 63, 64);                 \
    const float sn = (qg == 0) ? TNP1[0] : T[0];                       \
    const float nv = __shfl(sn, (lane + 16) & 63, 64);                 \
    const float ta0 = ((MT) == 0 && qg == 0) ? t4[3] : pv;             \
    const float tb3 = ((MT) == 4 && qg == 0) ? t0[0] : nv;             \
    float o0 = fmaf(CLL, ta0 + T[0] + T[1], cmt);                      \
    float o1 = fmaf(CLL, T[0] + T[1] + T[2], cmt);                     \
    float o2 = fmaf(CLL, T[1] + T[2] + T[3], cmt);                     \
    float o3 = fmaf(CLL, T[2] + T[3] + tb3, cmt);                      \
    o0 = fmaf(fmaxf(o0, 0.f), sc, sh);                                 \
    o1 = fmaf(fmaxf(o1, 0.f), sc, sh);                                 \
    o2 = fmaf(fmaxf(o2, 0.f), sc, sh);                                 \
    o3 = fmaf(fmaxf(o3, 0.f), sc, sh);                                 \
    if (RESID) { o0 += H[0]; o1 += H[1]; o2 += H[2]; o3 += H[3]; }     \
    H[0] = o0; H[1] = o1; H[2] = o2; H[3] = o3;                        \
  }

#define WPAIR(HW, MT, H)                                               \
  {                                                                    \
    const u32 pa = cvtpk(H[0], H[1]);                                  \
    const u32 pb = cvtpk(H[2], H[3]);                                  \
    (HW)[WADDR(MT, 0)] = (u16)pa;                                      \
    (HW)[WADDR(MT, 1)] = (u16)(pa >> 16);                              \
    (HW)[WADDR(MT, 2)] = (u16)pb;                                      \
    (HW)[WADDR(MT, 3)] = (u16)(pb >> 16);                              \
  }

// epilogue: master agg + stencil + bn/relu/resid in registers, then bf16 writes
#define EPILOG(RESID, WRITE, HBW)                                      \
  {                                                                    \
    float S = SUM4(t0) + SUM4(t1) + SUM4(t2) + SUM4(t3) + SUM4(t4);    \
    if (qg == 1) S -= t4[0]; /* exclude master t; pad rows are 0 */    \
    S += __shfl_xor(S, 16, 64);                                        \
    S += __shfl_xor(S, 32, 64);                                        \
    const float t68b = __shfl(t4[0], 16 + p15, 64);                    \
    const float cmt = fmaf(CML, t68b, bias);                           \
    float mv = fmaxf(fmaf(CML, S, fmaf(SELFM, t68b, bias)), 0.f);      \
    mv = fmaf(mv, sc, sh);                                             \
    if (RESID) mv += h4[0];                                            \
    STEP(0, t0, t4, t1, h0, RESID)                                     \
    STEP(1, t1, t0, t2, h1, RESID)                                     \
    STEP(2, t2, t1, t3, h2, RESID)                                     \
    STEP(3, t3, t2, t4, h3, RESID)                                     \
    STEP(4, t4, t3, t0, h4, RESID)                                     \
    if (qg == 1) h4[0] = mv; /* master h lives in slot [4][0] */       \
    if (WRITE) {                                                       \
      u16* hw_ = (HBW);                                                \
      WPAIR(hw_, 0, h0)                                                \
      WPAIR(hw_, 1, h1)                                                \
      WPAIR(hw_, 2, h2)                                                \
      WPAIR(hw_, 3, h3)                                                \
      if (qg == 0) { WPAIR(hw_, 4, h4) }                               \
      else if (qg == 1) hw_[68 * 64 + (c ^ 32)] = (u16)cvtpk(h4[0], h4[0]); \
    }                                                                  \
  }

#define MP(HR, MT, T)                                                  \
  {                                                                    \
    const short8 a0 = *(const short8*)&(HR)[(MT) * 1024 + ra0];        \
    const short8 a1 = *(const short8*)&(HR)[(MT) * 1024 + ra1];        \
    f32x4 acc = {0.f, 0.f, 0.f, 0.f};                                  \
    acc = __builtin_amdgcn_mfma_f32_16x16x32_bf16(a0, b0, acc, 0, 0, 0); \
    acc = __builtin_amdgcn_mfma_f32_16x16x32_bf16(a1, b1, acc, 0, 0, 0); \
    T = acc;                                                           \
  }

__launch_bounds__(256)
__global__ void gcn_fused(
    const float* __restrict__ x,
    const float* __restrict__ cfW, const float* __restrict__ cfb,
    const float* __restrict__ cmb, const float* __restrict__ clb,
    const float* __restrict__ aW1, const float* __restrict__ ab1,
    const float* __restrict__ aW2, const float* __restrict__ ab2,
    const float* __restrict__ f1W, const float* __restrict__ f1b,
    const float* __restrict__ f2W, const float* __restrict__ f2b,
    const u16* __restrict__ frag, const float* __restrict__ bns,
    float* __restrict__ out) {
  // LDS: 20480 + 1280 + 256 + 768 + 1024 = 23808 B
  __shared__ u16 hb[2][80 * 64];  // bf16 h double-buffer, rows 69..79 stay 0
  __shared__ float xl4[80 * 4];   // staged x, rows 69..79 = 0
  __shared__ float mrow[64];      // final master h
  __shared__ float gv[192];       // readout concat [mean|max|master*att]
  __shared__ float part[256];     // cross-wave partial buffer (att / fc1)

  const int tid = threadIdx.x;
  const int g = blockIdx.x;
  const int lane = tid & 63;
  const int wv = tid >> 6;
  const int p15 = lane & 15;
  const int qg = lane >> 4;
  const int c = wv * 16 + p15;            // this thread's feature column
  const int cq = c ^ ((qg & 1) << 5);     // write-swizzle base
  const int rsw = (p15 & 7) << 3;
  const int ra0 = (p15 * 64 + qg * 8) ^ rsw;        // A-frag kg=0 base
  const int ra1 = (p15 * 64 + 32 + qg * 8) ^ rsw;   // A-frag kg=1 base

  // ---- preload ALL per-layer scalars (hides global latency under staging)
  float lb[8], ls[8], lh[8];
  lb[0] = cfb[c]; ls[0] = bns[c]; lh[0] = bns[64 + c];
#pragma unroll
  for (int l = 1; l <= 6; ++l) {
    lb[l] = cmb[(l - 1) * 64 + c];
    ls[l] = bns[l * 128 + c];
    lh[l] = bns[l * 128 + 64 + c];
  }
  lb[7] = clb[c]; ls[7] = 1.f; lh[7] = 0.f;

  // prefetch layer-1 B fragments
  const u16* fb = frag + ((size_t)(0 * 4 + wv) * 2 * 64 + lane) * 8;
  short8 b0 = *(const short8*)fb;
  short8 b1 = *(const short8*)(fb + 512);

  // zero both hb buffers (pad rows must stay 0); stage x
  for (int i = tid; i < 5120; i += 256) ((u32*)hb)[i] = 0u;
  if (tid < 69)
    *(f32x4*)&xl4[tid * 4] = *(const f32x4*)&x[((size_t)g * 69 + tid) * 4];
  else if (tid < 80)
    *(f32x4*)&xl4[tid * 4] = (f32x4){0.f, 0.f, 0.f, 0.f};

  f32x4 t0, t1, t2, t3, t4;
  f32x4 h0, h1, h2, h3, h4;

  __syncthreads();

  // ---- layer 0: t = x @ W_first (exact fp32, K=4), nodes in MFMA layout
  {
    const float w0 = cfW[c], w1 = cfW[64 + c], w2 = cfW[128 + c], w3 = cfW[192 + c];
#define L0T(MT, T)                                                     \
    { _Pragma("unroll") for (int r = 0; r < 4; ++r) {                  \
        const f32x4 xv = *(const f32x4*)&xl4[(16 * (MT) + 4 * qg + r) * 4]; \
        T[r] = fmaf(xv[0], w0, fmaf(xv[1], w1, fmaf(xv[2], w2, xv[3] * w3))); } }
    L0T(0, t0) L0T(1, t1) L0T(2, t2) L0T(3, t3) L0T(4, t4)
#undef L0T
  }
  {
    const float bias = lb[0], sc = ls[0], sh = lh[0];
    EPILOG(false, true, &hb[0][0])
  }
  __syncthreads();

  // ---- layers 1..6: MFMA + register epilogue (bn + residual)
  // FULLY UNROLLED: buffer parity / frag offsets / MT all compile-time ->
  // ds offsets become immediates, write-address bases hoisted once.
#pragma unroll
  for (int l = 1; l <= 6; ++l) {
    const u16* fbn = frag + ((size_t)(l * 4 + wv) * 2 * 64 + lane) * 8;
    const short8 nb0 = *(const short8*)fbn;
    const short8 nb1 = *(const short8*)(fbn + 512);
    const u16* hr = &hb[(l + 1) & 1][0];
    __builtin_amdgcn_s_setprio(1);
    MP(hr, 0, t0) MP(hr, 1, t1) MP(hr, 2, t2) MP(hr, 3, t3) MP(hr, 4, t4)
    __builtin_amdgcn_s_setprio(0);
    b0 = nb0;
    b1 = nb1;
    const float bias = lb[l], sc = ls[l], sh = lh[l];
    EPILOG(true, true, &hb[l & 1][0])
    __syncthreads();
  }

  // ---- layer 7: MFMA + epilogue (no bn, no residual, no hb write)
  {
    const u16* hr = &hb[0][0];
    __builtin_amdgcn_s_setprio(1);
    MP(hr, 0, t0) MP(hr, 1, t1) MP(hr, 2, t2) MP(hr, 3, t3) MP(hr, 4, t4)
    __builtin_amdgcn_s_setprio(0);
    const float bias = lb[7], sc = ls[7], sh = lh[7];
    EPILOG(false, false, (u16*)nullptr)
  }

  // ---- readout: per-col landmark mean/max from registers
  {
    float s = SUM4(h0) + SUM4(h1) + SUM4(h2) + SUM4(h3);
    float mx = fmaxf(fmaxf(MAX4(h0), MAX4(h1)), fmaxf(MAX4(h2), MAX4(h3)));
    if (qg == 0) {  // only qg==0's mt=4 run (nodes 64..67) is valid landmarks
      s += SUM4(h4);
      mx = fmaxf(mx, MAX4(h4));
    }
    s += __shfl_xor(s, 16, 64);
    s += __shfl_xor(s, 32, 64);
    mx = fmaxf(mx, __shfl_xor(mx, 16, 64));
    mx = fmaxf(mx, __shfl_xor(mx, 32, 64));
    if (qg == 0) {
      gv[c] = s * (1.f / 68.f);
      gv[64 + c] = mx;
    }
    if (qg == 1) mrow[c] = h4[0];
  }
  __syncthreads();

  // ---- attention gate (distributed over all 4 waves)
  {
    float z = 0.f;
#pragma unroll
    for (int k = 0; k < 16; ++k)
      z = fmaf(mrow[wv * 16 + k], aW1[(wv * 16 + k) * 64 + lane], z);
    part[wv * 64 + lane] = z;
  }
  __syncthreads();
  if (tid < 64) {
    float z = part[tid] + part[64 + tid] + part[128 + tid] + part[192 + tid] + ab1[tid];
    z = fmaxf(z, 0.f);
    float pr = z * aW2[tid];
#pragma unroll
    for (int off = 32; off > 0; off >>= 1) pr += __shfl_xor(pr, off, 64);
    const float att = 1.f / (1.f + expf(-(pr + ab2[0])));
    gv[128 + tid] = mrow[tid] * att;
  }
  __syncthreads();

  // ---- fc1 partials (distributed over all 4 waves)
  {
    float a = 0.f;
#pragma unroll
    for (int i = 0; i < 48; ++i)
      a = fmaf(gv[wv * 48 + i], f1W[(wv * 48 + i) * 64 + lane], a);
    part[wv * 64 + lane] = a;
  }
  __syncthreads();
  if (tid < 64) {
    float a = part[tid] + part[64 + tid] + part[128 + tid] + part[192 + tid] + f1b[tid];
    const float y = fmaxf(a, 0.f);
    float po[7];
#pragma unroll
    for (int o = 0; o < 7; ++o) po[o] = y * f2W[tid * 7 + o];
#pragma unroll
    for (int o = 0; o < 7; ++o)
#pragma unroll
      for (int off = 32; off > 0; off >>= 1) po[o] += __shfl_xor(po[o], off, 64);
    if (tid == 0) {
#pragma unroll
      for (int o = 0; o < 7; ++o) out[(size_t)g * 7 + o] = po[o] + f2b[o];
    }
  }
}

extern "C" void kernel_launch(void* const* d_in, const int* in_sizes, int n_in,
                              void* d_out, int out_size, void* d_ws, size_t ws_size,
                              hipStream_t stream) {
  (void)in_sizes; (void)n_in; (void)ws_size;
  const float* x   = (const float*)d_in[0];
  const float* cfW = (const float*)d_in[4];
  const float* cfb = (const float*)d_in[5];
  const float* cmW = (const float*)d_in[6];
  const float* cmb = (const float*)d_in[7];
  const float* clW = (const float*)d_in[8];
  const float* clb = (const float*)d_in[9];
  const float* bng = (const float*)d_in[10];
  const float* bnb = (const float*)d_in[11];
  const float* bnm = (const float*)d_in[12];
  const float* bnv = (const float*)d_in[13];
  const float* aW1 = (const float*)d_in[14];
  const float* ab1 = (const float*)d_in[15];
  const float* aW2 = (const float*)d_in[16];
  const float* ab2 = (const float*)d_in[17];
  const float* f1W = (const float*)d_in[18];
  const float* f1b = (const float*)d_in[19];
  const float* f2W = (const float*)d_in[20];
  const float* f2b = (const float*)d_in[21];

  u16* frag = (u16*)d_ws;                      // 57344 B
  float* bns = (float*)((char*)d_ws + 57344);  // 7*128 floats
  const int ngraphs = out_size / 7;

  prep<<<dim3(16), dim3(256), 0, stream>>>(cmW, clW, bng, bnb, bnm, bnv, frag, bns);
  gcn_fused<<<dim3(ngraphs), dim3(256), 0, stream>>>(
      x, cfW, cfb, cmb, clb, aW1, ab1, aW2, ab2, f1W, f1b, f2W, f2b,
      frag, bns, (float*)d_out);
}